// Round 1
// baseline (851.760 us; speedup 1.0000x reference)
//
#include <hip/hip_runtime.h>

// ---------------------------------------------------------------------------
// GCNEncoder: 3-layer GCN with symmetric norm and self-loops.
//   per layer: h = (x * out_norm) @ W ; agg = segsum(h[src], dst) + h (self)
//              out = agg * in_norm + b ; relu (layers 1,2)
// Strategy: build CSR (by dst) once per call -> aggregation is pure gather.
// ---------------------------------------------------------------------------

#define NFEAT 128

__global__ void count_kernel(const int* __restrict__ src, const int* __restrict__ dst,
                             int* __restrict__ out_cnt, int* __restrict__ in_cnt, int E) {
    int i = blockIdx.x * blockDim.x + threadIdx.x;
    if (i < E) {
        atomicAdd(&out_cnt[src[i]], 1);
        atomicAdd(&in_cnt[dst[i]], 1);
    }
}

__global__ void norm_kernel(const int* __restrict__ out_cnt, const int* __restrict__ in_cnt,
                            float* __restrict__ out_norm, float* __restrict__ in_norm, int n) {
    int i = blockIdx.x * blockDim.x + threadIdx.x;
    if (i < n) {
        // +1 for self-loop; degree >= 1 so the reference clip is a no-op
        out_norm[i] = rsqrtf((float)(out_cnt[i] + 1));
        in_norm[i]  = rsqrtf((float)(in_cnt[i] + 1));
    }
}

// Single-block exclusive scan over n ints (n ~ 100k): wave shuffles + 16-wave combine.
__global__ __launch_bounds__(1024) void scan_kernel(const int* __restrict__ cnt,
                                                    int* __restrict__ row_ptr, int n) {
    const int tid  = threadIdx.x;
    const int lane = tid & 63;
    const int wid  = tid >> 6;   // 0..15
    __shared__ int wsum[16];
    int carry = 0;
    for (int base = 0; base < n; base += 1024) {
        int i = base + tid;
        int v = (i < n) ? cnt[i] : 0;
        int incl = v;
        #pragma unroll
        for (int off = 1; off < 64; off <<= 1) {
            int t = __shfl_up(incl, off, 64);
            if (lane >= off) incl += t;
        }
        if (lane == 63) wsum[wid] = incl;
        __syncthreads();
        if (wid == 0) {
            int wv = (lane < 16) ? wsum[lane] : 0;
            #pragma unroll
            for (int off = 1; off < 16; off <<= 1) {
                int t = __shfl_up(wv, off, 64);
                if (lane >= off) wv += t;
            }
            if (lane < 16) wsum[lane] = wv;
        }
        __syncthreads();
        int woff  = (wid > 0) ? wsum[wid - 1] : 0;
        if (i < n) row_ptr[i] = carry + woff + incl - v;   // exclusive
        int total = wsum[15];
        __syncthreads();   // protect wsum before next iteration overwrites it
        carry += total;
    }
    if (tid == 0) row_ptr[n] = carry;
}

__global__ void fill_kernel(const int* __restrict__ src, const int* __restrict__ dst,
                            int* __restrict__ cursor, int* __restrict__ col_idx, int E) {
    int i = blockIdx.x * blockDim.x + threadIdx.x;
    if (i < E) {
        int d = dst[i];
        int pos = atomicAdd(&cursor[d], 1);
        col_idx[pos] = src[i];
    }
}

// h[BM rows x BN] = (x * out_norm[:,None]) @ W,  K = 128 fixed, BK = 32.
// 256 threads, per-thread 8x(BN/32) register tile.
template <int BN>
__global__ __launch_bounds__(256) void gemm_norm_kernel(const float* __restrict__ x,
                                                        const float* __restrict__ W,
                                                        const float* __restrict__ out_norm,
                                                        float* __restrict__ h, int n_rows) {
    constexpr int BM = 64, BK = 32;
    constexpr int TN = BN / 32;                 // 4 (BN=128) or 2 (BN=64)
    __shared__ float xs[BK][BM + 4];            // transposed x tile; +4 keeps 16B align, breaks bank stride
    __shared__ float wsh[BK][BN];

    const int tid  = threadIdx.x;
    const int row0 = blockIdx.x * BM;

    // staging mapping: thread owns row srow, k-offset skoff (2 float4 = 8 floats)
    const int srow  = tid >> 2;                 // 0..63
    const int skoff = (tid & 3) * 8;            // 0,8,16,24
    const int grow  = row0 + srow;
    const bool rowok = (grow < n_rows);
    const float norm = rowok ? out_norm[grow] : 0.0f;
    const float* xrow = x + (size_t)grow * NFEAT;

    // compute mapping
    const int cg = tid & 31;                    // col group 0..31
    const int rg = tid >> 5;                    // row group 0..7 (8 rows each)

    float acc[8][TN];
    #pragma unroll
    for (int m = 0; m < 8; ++m)
        #pragma unroll
        for (int n = 0; n < TN; ++n) acc[m][n] = 0.0f;

    for (int k0 = 0; k0 < NFEAT; k0 += BK) {
        float v[8];
        if (rowok) {
            float4 p0 = *(const float4*)(xrow + k0 + skoff);
            float4 p1 = *(const float4*)(xrow + k0 + skoff + 4);
            v[0]=p0.x; v[1]=p0.y; v[2]=p0.z; v[3]=p0.w;
            v[4]=p1.x; v[5]=p1.y; v[6]=p1.z; v[7]=p1.w;
        } else {
            #pragma unroll
            for (int j = 0; j < 8; ++j) v[j] = 0.0f;
        }
        #pragma unroll
        for (int j = 0; j < 8; ++j) xs[skoff + j][srow] = v[j] * norm;

        constexpr int WLOAD = (BK * BN) / (256 * 4);  // float4s per thread
        #pragma unroll
        for (int t = 0; t < WLOAD; ++t) {
            int e  = (tid + t * 256) * 4;
            int kk = e / BN, cc = e % BN;
            float4 wv = *(const float4*)(W + (size_t)(k0 + kk) * BN + cc);
            *(float4*)&wsh[kk][cc] = wv;
        }
        __syncthreads();

        #pragma unroll
        for (int kk = 0; kk < BK; ++kk) {
            float a[8];
            float4 a0 = *(const float4*)&xs[kk][rg * 8];
            float4 a1 = *(const float4*)&xs[kk][rg * 8 + 4];
            a[0]=a0.x; a[1]=a0.y; a[2]=a0.z; a[3]=a0.w;
            a[4]=a1.x; a[5]=a1.y; a[6]=a1.z; a[7]=a1.w;
            float b[TN];
            if constexpr (TN == 4) {
                float4 bv = *(const float4*)&wsh[kk][cg * 4];
                b[0]=bv.x; b[1]=bv.y; b[2]=bv.z; b[3]=bv.w;
            } else {
                float2 bv = *(const float2*)&wsh[kk][cg * 2];
                b[0]=bv.x; b[1]=bv.y;
            }
            #pragma unroll
            for (int m = 0; m < 8; ++m)
                #pragma unroll
                for (int n = 0; n < TN; ++n) acc[m][n] += a[m] * b[n];
        }
        __syncthreads();
    }

    #pragma unroll
    for (int m = 0; m < 8; ++m) {
        int r = row0 + rg * 8 + m;
        if (r < n_rows) {
            if constexpr (TN == 4) {
                float4 o; o.x=acc[m][0]; o.y=acc[m][1]; o.z=acc[m][2]; o.w=acc[m][3];
                *(float4*)(h + (size_t)r * BN + cg * 4) = o;
            } else {
                float2 o; o.x=acc[m][0]; o.y=acc[m][1];
                *(float2*)(h + (size_t)r * BN + cg * 2) = o;
            }
        }
    }
}

// Gather aggregation + epilogue: out = (sum_{in-edges} h[src] + h[node]) * in_norm + b [, relu]
template <int DOUT, bool RELU>
__global__ __launch_bounds__(256) void agg_kernel(const float* __restrict__ h,
                                                  const int* __restrict__ row_ptr,
                                                  const int* __restrict__ col_idx,
                                                  const float* __restrict__ in_norm,
                                                  const float* __restrict__ bias,
                                                  float* __restrict__ out, int n) {
    constexpr int TPN = DOUT / 4;      // threads per node (float4 each)
    constexpr int NPB = 256 / TPN;     // nodes per block
    const int tid  = threadIdx.x;
    const int sub  = tid / TPN;
    const int c    = (tid % TPN) * 4;
    const int node = blockIdx.x * NPB + sub;
    if (node >= n) return;

    float4 acc = *(const float4*)(h + (size_t)node * DOUT + c);   // self-loop message
    int e  = row_ptr[node];
    int e1 = row_ptr[node + 1];
    for (; e + 1 < e1; e += 2) {
        int s0 = col_idx[e];
        int s1 = col_idx[e + 1];
        float4 m0 = *(const float4*)(h + (size_t)s0 * DOUT + c);
        float4 m1 = *(const float4*)(h + (size_t)s1 * DOUT + c);
        acc.x += m0.x + m1.x; acc.y += m0.y + m1.y;
        acc.z += m0.z + m1.z; acc.w += m0.w + m1.w;
    }
    if (e < e1) {
        int s0 = col_idx[e];
        float4 m0 = *(const float4*)(h + (size_t)s0 * DOUT + c);
        acc.x += m0.x; acc.y += m0.y; acc.z += m0.z; acc.w += m0.w;
    }
    float inn = in_norm[node];
    float4 bv = *(const float4*)(bias + c);
    float4 r;
    r.x = acc.x * inn + bv.x; r.y = acc.y * inn + bv.y;
    r.z = acc.z * inn + bv.z; r.w = acc.w * inn + bv.w;
    if (RELU) {
        r.x = fmaxf(r.x, 0.0f); r.y = fmaxf(r.y, 0.0f);
        r.z = fmaxf(r.z, 0.0f); r.w = fmaxf(r.w, 0.0f);
    }
    *(float4*)(out + (size_t)node * DOUT + c) = r;
}

extern "C" void kernel_launch(void* const* d_in, const int* in_sizes, int n_in,
                              void* d_out, int out_size, void* d_ws, size_t ws_size,
                              hipStream_t stream) {
    const float* feat = (const float*)d_in[0];
    const int*   src  = (const int*)d_in[1];
    const int*   dst  = (const int*)d_in[2];
    const float* W1   = (const float*)d_in[3];
    const float* b1   = (const float*)d_in[4];
    const float* W2   = (const float*)d_in[5];
    const float* b2   = (const float*)d_in[6];
    const float* W3   = (const float*)d_in[7];
    const float* b3   = (const float*)d_in[8];

    const int N = in_sizes[0] / NFEAT;   // 100000
    const int E = in_sizes[1];           // 1600000

    char* ws = (char*)d_ws;
    auto alloc = [&](size_t bytes) {
        char* p = ws;
        ws += (bytes + 255) & ~(size_t)255;
        return p;
    };
    int*   out_cnt  = (int*)alloc((size_t)N * 4);
    int*   in_cnt   = (int*)alloc((size_t)N * 4);
    float* out_norm = (float*)alloc((size_t)N * 4);
    float* in_norm  = (float*)alloc((size_t)N * 4);
    int*   row_ptr  = (int*)alloc((size_t)(N + 1) * 4);
    int*   cursor   = (int*)alloc((size_t)N * 4);
    int*   col_idx  = (int*)alloc((size_t)E * 4);
    float* bufA     = (float*)alloc((size_t)N * NFEAT * 4);
    float* bufB     = (float*)alloc((size_t)N * NFEAT * 4);

    // --- graph preprocessing (per call; inputs are restored each call) ---
    hipMemsetAsync(out_cnt, 0, (size_t)N * 4, stream);
    hipMemsetAsync(in_cnt, 0, (size_t)N * 4, stream);
    count_kernel<<<(E + 255) / 256, 256, 0, stream>>>(src, dst, out_cnt, in_cnt, E);
    norm_kernel<<<(N + 255) / 256, 256, 0, stream>>>(out_cnt, in_cnt, out_norm, in_norm, N);
    scan_kernel<<<1, 1024, 0, stream>>>(in_cnt, row_ptr, N);
    hipMemcpyAsync(cursor, row_ptr, (size_t)N * 4, hipMemcpyDeviceToDevice, stream);
    fill_kernel<<<(E + 255) / 256, 256, 0, stream>>>(src, dst, cursor, col_idx, E);

    const int gb = (N + 63) / 64;
    // layer 1
    gemm_norm_kernel<128><<<gb, 256, 0, stream>>>(feat, W1, out_norm, bufA, N);
    agg_kernel<128, true><<<(N + 7) / 8, 256, 0, stream>>>(bufA, row_ptr, col_idx, in_norm, b1, bufB, N);
    // layer 2
    gemm_norm_kernel<128><<<gb, 256, 0, stream>>>(bufB, W2, out_norm, bufA, N);
    agg_kernel<128, true><<<(N + 7) / 8, 256, 0, stream>>>(bufA, row_ptr, col_idx, in_norm, b2, bufB, N);
    // layer 3 (no relu, write d_out)
    gemm_norm_kernel<64><<<gb, 256, 0, stream>>>(bufB, W3, out_norm, bufA, N);
    agg_kernel<64, false><<<(N + 15) / 16, 256, 0, stream>>>(bufA, row_ptr, col_idx, in_norm, b3,
                                                             (float*)d_out, N);
}

// Round 2
// 699.702 us; speedup vs baseline: 1.2173x; 1.2173x over previous
//
#include <hip/hip_runtime.h>

// ---------------------------------------------------------------------------
// GCNEncoder: 3-layer GCN with symmetric norm and self-loops.
//   per layer: h = (x * out_norm) @ W ; agg = segsum(h[src], dst) + h (self)
//              out = agg * in_norm + b ; relu (layers 1,2)
// CSR build (by dst) -> aggregation is pure gather.
// R1: rank-based fill (no atomics in fill; rank captured in count_kernel's
//     atomicAdd return) + multi-block scan (was single-block, serialized).
// ---------------------------------------------------------------------------

#define NFEAT 128

__global__ void count_kernel(const int* __restrict__ src, const int* __restrict__ dst,
                             int* __restrict__ out_cnt, int* __restrict__ in_cnt,
                             int* __restrict__ rank, int E) {
    int i = blockIdx.x * blockDim.x + threadIdx.x;
    if (i < E) {
        atomicAdd(&out_cnt[src[i]], 1);
        rank[i] = atomicAdd(&in_cnt[dst[i]], 1);   // unique slot within dst bucket
    }
}

__global__ void norm_kernel(const int* __restrict__ out_cnt, const int* __restrict__ in_cnt,
                            float* __restrict__ out_norm, float* __restrict__ in_norm, int n) {
    int i = blockIdx.x * blockDim.x + threadIdx.x;
    if (i < n) {
        // +1 for self-loop; degree >= 1 so the reference clip is a no-op
        out_norm[i] = rsqrtf((float)(out_cnt[i] + 1));
        in_norm[i]  = rsqrtf((float)(in_cnt[i] + 1));
    }
}

// --- multi-block exclusive scan: scan1 (per-block) -> scan2 (block sums) -> scan3 (add) ---
__global__ __launch_bounds__(256) void scan1_kernel(const int* __restrict__ cnt,
                                                    int* __restrict__ excl,      // row_ptr[0..n)
                                                    int* __restrict__ blk_sum, int n) {
    const int tid = threadIdx.x, lane = tid & 63, wid = tid >> 6;  // 4 waves
    const int i = blockIdx.x * 256 + tid;
    int v = (i < n) ? cnt[i] : 0;
    int incl = v;
    #pragma unroll
    for (int off = 1; off < 64; off <<= 1) {
        int t = __shfl_up(incl, off, 64);
        if (lane >= off) incl += t;
    }
    __shared__ int ws[4];
    if (lane == 63) ws[wid] = incl;
    __syncthreads();
    int woff = 0;
    #pragma unroll
    for (int w = 0; w < 3; ++w) if (w < wid) woff += ws[w];
    if (i < n) excl[i] = woff + incl - v;
    if (tid == 0) blk_sum[blockIdx.x] = ws[0] + ws[1] + ws[2] + ws[3];
}

__global__ __launch_bounds__(512) void scan2_kernel(int* __restrict__ blk,
                                                    int* __restrict__ grand_total, int nb) {
    const int tid = threadIdx.x, lane = tid & 63, wid = tid >> 6;  // 8 waves
    int v = (tid < nb) ? blk[tid] : 0;
    int incl = v;
    #pragma unroll
    for (int off = 1; off < 64; off <<= 1) {
        int t = __shfl_up(incl, off, 64);
        if (lane >= off) incl += t;
    }
    __shared__ int ws[8];
    if (lane == 63) ws[wid] = incl;
    __syncthreads();
    int woff = 0;
    #pragma unroll
    for (int w = 0; w < 7; ++w) if (w < wid) woff += ws[w];
    int excl = woff + incl - v;
    if (tid < nb) blk[tid] = excl;
    if (tid == nb - 1) *grand_total = excl + v;   // row_ptr[n]
}

__global__ void scan3_kernel(int* __restrict__ excl, const int* __restrict__ blk, int n) {
    int i = blockIdx.x * 256 + threadIdx.x;
    if (i < n) excl[i] += blk[blockIdx.x];
}

// Atomic-free fill: position = row_ptr[dst] + rank(edge).
__global__ void fill_kernel(const int* __restrict__ src, const int* __restrict__ dst,
                            const int* __restrict__ rank, const int* __restrict__ row_ptr,
                            int* __restrict__ col_idx, int E) {
    int i = blockIdx.x * blockDim.x + threadIdx.x;
    if (i < E) {
        int d = dst[i];
        col_idx[row_ptr[d] + rank[i]] = src[i];
    }
}

// h[BM rows x BN] = (x * out_norm[:,None]) @ W,  K = 128 fixed, BK = 32.
// 256 threads, per-thread 8x(BN/32) register tile.
template <int BN>
__global__ __launch_bounds__(256) void gemm_norm_kernel(const float* __restrict__ x,
                                                        const float* __restrict__ W,
                                                        const float* __restrict__ out_norm,
                                                        float* __restrict__ h, int n_rows) {
    constexpr int BM = 64, BK = 32;
    constexpr int TN = BN / 32;                 // 4 (BN=128) or 2 (BN=64)
    __shared__ float xs[BK][BM + 4];            // transposed x tile
    __shared__ float wsh[BK][BN];

    const int tid  = threadIdx.x;
    const int row0 = blockIdx.x * BM;

    const int srow  = tid >> 2;                 // 0..63
    const int skoff = (tid & 3) * 8;            // 0,8,16,24
    const int grow  = row0 + srow;
    const bool rowok = (grow < n_rows);
    const float norm = rowok ? out_norm[grow] : 0.0f;
    const float* xrow = x + (size_t)grow * NFEAT;

    const int cg = tid & 31;                    // col group 0..31
    const int rg = tid >> 5;                    // row group 0..7 (8 rows each)

    float acc[8][TN];
    #pragma unroll
    for (int m = 0; m < 8; ++m)
        #pragma unroll
        for (int n = 0; n < TN; ++n) acc[m][n] = 0.0f;

    for (int k0 = 0; k0 < NFEAT; k0 += BK) {
        float v[8];
        if (rowok) {
            float4 p0 = *(const float4*)(xrow + k0 + skoff);
            float4 p1 = *(const float4*)(xrow + k0 + skoff + 4);
            v[0]=p0.x; v[1]=p0.y; v[2]=p0.z; v[3]=p0.w;
            v[4]=p1.x; v[5]=p1.y; v[6]=p1.z; v[7]=p1.w;
        } else {
            #pragma unroll
            for (int j = 0; j < 8; ++j) v[j] = 0.0f;
        }
        #pragma unroll
        for (int j = 0; j < 8; ++j) xs[skoff + j][srow] = v[j] * norm;

        constexpr int WLOAD = (BK * BN) / (256 * 4);  // float4s per thread
        #pragma unroll
        for (int t = 0; t < WLOAD; ++t) {
            int e  = (tid + t * 256) * 4;
            int kk = e / BN, cc = e % BN;
            float4 wv = *(const float4*)(W + (size_t)(k0 + kk) * BN + cc);
            *(float4*)&wsh[kk][cc] = wv;
        }
        __syncthreads();

        #pragma unroll
        for (int kk = 0; kk < BK; ++kk) {
            float a[8];
            float4 a0 = *(const float4*)&xs[kk][rg * 8];
            float4 a1 = *(const float4*)&xs[kk][rg * 8 + 4];
            a[0]=a0.x; a[1]=a0.y; a[2]=a0.z; a[3]=a0.w;
            a[4]=a1.x; a[5]=a1.y; a[6]=a1.z; a[7]=a1.w;
            float b[TN];
            if constexpr (TN == 4) {
                float4 bv = *(const float4*)&wsh[kk][cg * 4];
                b[0]=bv.x; b[1]=bv.y; b[2]=bv.z; b[3]=bv.w;
            } else {
                float2 bv = *(const float2*)&wsh[kk][cg * 2];
                b[0]=bv.x; b[1]=bv.y;
            }
            #pragma unroll
            for (int m = 0; m < 8; ++m)
                #pragma unroll
                for (int n = 0; n < TN; ++n) acc[m][n] += a[m] * b[n];
        }
        __syncthreads();
    }

    #pragma unroll
    for (int m = 0; m < 8; ++m) {
        int r = row0 + rg * 8 + m;
        if (r < n_rows) {
            if constexpr (TN == 4) {
                float4 o; o.x=acc[m][0]; o.y=acc[m][1]; o.z=acc[m][2]; o.w=acc[m][3];
                *(float4*)(h + (size_t)r * BN + cg * 4) = o;
            } else {
                float2 o; o.x=acc[m][0]; o.y=acc[m][1];
                *(float2*)(h + (size_t)r * BN + cg * 2) = o;
            }
        }
    }
}

// Gather aggregation + epilogue: out = (sum_{in-edges} h[src] + h[node]) * in_norm + b [, relu]
template <int DOUT, bool RELU>
__global__ __launch_bounds__(256) void agg_kernel(const float* __restrict__ h,
                                                  const int* __restrict__ row_ptr,
                                                  const int* __restrict__ col_idx,
                                                  const float* __restrict__ in_norm,
                                                  const float* __restrict__ bias,
                                                  float* __restrict__ out, int n) {
    constexpr int TPN = DOUT / 4;      // threads per node (float4 each)
    constexpr int NPB = 256 / TPN;     // nodes per block
    const int tid  = threadIdx.x;
    const int sub  = tid / TPN;
    const int c    = (tid % TPN) * 4;
    const int node = blockIdx.x * NPB + sub;
    if (node >= n) return;

    float4 acc = *(const float4*)(h + (size_t)node * DOUT + c);   // self-loop message
    int e  = row_ptr[node];
    int e1 = row_ptr[node + 1];
    for (; e + 1 < e1; e += 2) {
        int s0 = col_idx[e];
        int s1 = col_idx[e + 1];
        float4 m0 = *(const float4*)(h + (size_t)s0 * DOUT + c);
        float4 m1 = *(const float4*)(h + (size_t)s1 * DOUT + c);
        acc.x += m0.x + m1.x; acc.y += m0.y + m1.y;
        acc.z += m0.z + m1.z; acc.w += m0.w + m1.w;
    }
    if (e < e1) {
        int s0 = col_idx[e];
        float4 m0 = *(const float4*)(h + (size_t)s0 * DOUT + c);
        acc.x += m0.x; acc.y += m0.y; acc.z += m0.z; acc.w += m0.w;
    }
    float inn = in_norm[node];
    float4 bv = *(const float4*)(bias + c);
    float4 r;
    r.x = acc.x * inn + bv.x; r.y = acc.y * inn + bv.y;
    r.z = acc.z * inn + bv.z; r.w = acc.w * inn + bv.w;
    if (RELU) {
        r.x = fmaxf(r.x, 0.0f); r.y = fmaxf(r.y, 0.0f);
        r.z = fmaxf(r.z, 0.0f); r.w = fmaxf(r.w, 0.0f);
    }
    *(float4*)(out + (size_t)node * DOUT + c) = r;
}

extern "C" void kernel_launch(void* const* d_in, const int* in_sizes, int n_in,
                              void* d_out, int out_size, void* d_ws, size_t ws_size,
                              hipStream_t stream) {
    const float* feat = (const float*)d_in[0];
    const int*   src  = (const int*)d_in[1];
    const int*   dst  = (const int*)d_in[2];
    const float* W1   = (const float*)d_in[3];
    const float* b1   = (const float*)d_in[4];
    const float* W2   = (const float*)d_in[5];
    const float* b2   = (const float*)d_in[6];
    const float* W3   = (const float*)d_in[7];
    const float* b3   = (const float*)d_in[8];

    const int N = in_sizes[0] / NFEAT;   // 100000
    const int E = in_sizes[1];           // 1600000

    char* ws = (char*)d_ws;
    auto alloc = [&](size_t bytes) {
        char* p = ws;
        ws += (bytes + 255) & ~(size_t)255;
        return p;
    };
    int*   out_cnt  = (int*)alloc((size_t)N * 4);
    int*   in_cnt   = (int*)alloc((size_t)N * 4);
    float* out_norm = (float*)alloc((size_t)N * 4);
    float* in_norm  = (float*)alloc((size_t)N * 4);
    int*   row_ptr  = (int*)alloc((size_t)(N + 1) * 4);
    int*   blk_sum  = (int*)alloc((size_t)1024 * 4);
    int*   col_idx  = (int*)alloc((size_t)E * 4);
    float* bufA     = (float*)alloc((size_t)N * NFEAT * 4);
    float* bufB     = (float*)alloc((size_t)N * NFEAT * 4);
    int*   rank     = (int*)bufA;        // alias: bufA unused until layer-1 GEMM

    const int nb = (N + 255) / 256;      // scan blocking (391)

    // --- graph preprocessing (per call; inputs restored each call) ---
    hipMemsetAsync(out_cnt, 0, (size_t)N * 4, stream);
    hipMemsetAsync(in_cnt, 0, (size_t)N * 4, stream);
    count_kernel<<<(E + 255) / 256, 256, 0, stream>>>(src, dst, out_cnt, in_cnt, rank, E);
    norm_kernel<<<(N + 255) / 256, 256, 0, stream>>>(out_cnt, in_cnt, out_norm, in_norm, N);
    scan1_kernel<<<nb, 256, 0, stream>>>(in_cnt, row_ptr, blk_sum, N);
    scan2_kernel<<<1, 512, 0, stream>>>(blk_sum, row_ptr + N, nb);
    scan3_kernel<<<nb, 256, 0, stream>>>(row_ptr, blk_sum, N);
    fill_kernel<<<(E + 255) / 256, 256, 0, stream>>>(src, dst, rank, row_ptr, col_idx, E);

    const int gb = (N + 63) / 64;
    // layer 1
    gemm_norm_kernel<128><<<gb, 256, 0, stream>>>(feat, W1, out_norm, bufA, N);
    agg_kernel<128, true><<<(N + 7) / 8, 256, 0, stream>>>(bufA, row_ptr, col_idx, in_norm, b1, bufB, N);
    // layer 2
    gemm_norm_kernel<128><<<gb, 256, 0, stream>>>(bufB, W2, out_norm, bufA, N);
    agg_kernel<128, true><<<(N + 7) / 8, 256, 0, stream>>>(bufA, row_ptr, col_idx, in_norm, b2, bufB, N);
    // layer 3 (no relu, write d_out)
    gemm_norm_kernel<64><<<gb, 256, 0, stream>>>(bufB, W3, out_norm, bufA, N);
    agg_kernel<64, false><<<(N + 15) / 16, 256, 0, stream>>>(bufA, row_ptr, col_idx, in_norm, b3,
                                                             (float*)d_out, N);
}